// Round 1
// baseline (1087.435 us; speedup 1.0000x reference)
//
#include <hip/hip_runtime.h>

#define NR 16384   // B*S rows
#define VD 1024    // value dim
#define ED 256     // embed dim
#define KC 8192    // codebook size
#define NSPLIT 4   // code-range splits for the distance kernel

// ---------------- projection: C[r][e] = sum_v A[r][v]*W[e][v] + b[e] ----------------
// 64x64 tile, 256 threads, 4x4 micro-tile, depth chunks of 32.
__global__ __launch_bounds__(256) void proj_kernel(
    const float* __restrict__ A, const float* __restrict__ W,
    const float* __restrict__ bias, float* __restrict__ C)
{
    __shared__ float As[32][64];
    __shared__ float Bs[32][64];
    const int rowbase = blockIdx.x * 64;
    const int colbase = blockIdx.y * 64;
    const int t = threadIdx.x;
    const int tx = t & 15, ty = t >> 4;
    float acc[4][4] = {};
    for (int dc = 0; dc < VD; dc += 32) {
        #pragma unroll
        for (int i = 0; i < 2; ++i) {
            int idx = i * 256 + t;        // 0..511
            int r  = idx >> 3;            // 0..63
            int dq = idx & 7;             // depth quad
            float4 va = *(const float4*)&A[(size_t)(rowbase + r) * VD + dc + dq * 4];
            As[dq*4+0][r] = va.x; As[dq*4+1][r] = va.y;
            As[dq*4+2][r] = va.z; As[dq*4+3][r] = va.w;
            float4 vw = *(const float4*)&W[(size_t)(colbase + r) * VD + dc + dq * 4];
            Bs[dq*4+0][r] = vw.x; Bs[dq*4+1][r] = vw.y;
            Bs[dq*4+2][r] = vw.z; Bs[dq*4+3][r] = vw.w;
        }
        __syncthreads();
        #pragma unroll
        for (int d = 0; d < 32; ++d) {
            float a[4], bb[4];
            *(float4*)a  = *(const float4*)&As[d][ty * 4];
            *(float4*)bb = *(const float4*)&Bs[d][tx * 4];
            #pragma unroll
            for (int i = 0; i < 4; ++i)
                #pragma unroll
                for (int j = 0; j < 4; ++j)
                    acc[i][j] = fmaf(a[i], bb[j], acc[i][j]);
        }
        __syncthreads();
    }
    #pragma unroll
    for (int i = 0; i < 4; ++i) {
        int row = rowbase + ty * 4 + i;
        #pragma unroll
        for (int j = 0; j < 4; ++j) {
            int col = colbase + tx * 4 + j;
            C[(size_t)row * ED + col] = acc[i][j] + bias[col];
        }
    }
}

// ---------------- codebook norms: cnorm[k] = sum_e CB[k][e]^2 (f64 accum) ----------------
__global__ __launch_bounds__(256) void cnorm_kernel(
    const float* __restrict__ CB, float* __restrict__ cnorm)
{
    const int t = threadIdx.x;
    const int lane = t & 63;
    const int w = t >> 6;
    const int code = blockIdx.x * 4 + w;
    float4 c = *(const float4*)&CB[(size_t)code * ED + lane * 4];
    double s = (double)c.x * c.x + (double)c.y * c.y + (double)c.z * c.z + (double)c.w * c.w;
    #pragma unroll
    for (int off = 32; off; off >>= 1) s += __shfl_down(s, off, 64);
    if (lane == 0) cnorm[code] = (float)s;
}

// ---------------- fused distance + argmin ----------------
// d2(r,k) = cnorm[k] - 2 * dot(P[r], CB[k])   (||p||^2 dropped: constant per row)
// 128 rows x 128 codes tile, 256 threads, 8x8 micro. Each block scans KC/NSPLIT codes,
// keeps running (min,idx) per row, reduces across the 16 code-threads at the end.
__global__ __launch_bounds__(256) void dist_kernel(
    const float* __restrict__ P, const float* __restrict__ CB,
    const float* __restrict__ cnorm,
    float* __restrict__ pmin, int* __restrict__ pidx)
{
    __shared__ float As[32][128];
    __shared__ float Bs[32][128];
    const int rowbase = blockIdx.x * 128;
    const int split = blockIdx.y;
    const int codebase0 = split * (KC / NSPLIT);
    const int t = threadIdx.x;
    const int tx = t & 15, ty = t >> 4;
    float runmin[8];
    int runidx[8];
    #pragma unroll
    for (int i = 0; i < 8; ++i) { runmin[i] = 3.4e38f; runidx[i] = 0x7fffffff; }

    for (int kc = 0; kc < KC / NSPLIT; kc += 128) {
        const int codebase = codebase0 + kc;
        float acc[8][8] = {};
        for (int dc = 0; dc < ED; dc += 32) {
            #pragma unroll
            for (int i = 0; i < 4; ++i) {
                int idx = i * 256 + t;    // 0..1023
                int r  = idx >> 3;        // 0..127
                int dq = idx & 7;
                float4 va = *(const float4*)&P[(size_t)(rowbase + r) * ED + dc + dq * 4];
                As[dq*4+0][r] = va.x; As[dq*4+1][r] = va.y;
                As[dq*4+2][r] = va.z; As[dq*4+3][r] = va.w;
                float4 vb = *(const float4*)&CB[(size_t)(codebase + r) * ED + dc + dq * 4];
                Bs[dq*4+0][r] = vb.x; Bs[dq*4+1][r] = vb.y;
                Bs[dq*4+2][r] = vb.z; Bs[dq*4+3][r] = vb.w;
            }
            __syncthreads();
            #pragma unroll
            for (int d = 0; d < 32; ++d) {
                float a[8], bb[8];
                *(float4*)&a[0]  = *(const float4*)&As[d][ty * 8];
                *(float4*)&a[4]  = *(const float4*)&As[d][ty * 8 + 4];
                *(float4*)&bb[0] = *(const float4*)&Bs[d][tx * 8];
                *(float4*)&bb[4] = *(const float4*)&Bs[d][tx * 8 + 4];
                #pragma unroll
                for (int i = 0; i < 8; ++i)
                    #pragma unroll
                    for (int j = 0; j < 8; ++j)
                        acc[i][j] = fmaf(a[i], bb[j], acc[i][j]);
            }
            __syncthreads();
        }
        // argmin epilogue (codes scanned in increasing order -> strict < keeps first)
        #pragma unroll
        for (int j = 0; j < 8; ++j) {
            int code = codebase + tx * 8 + j;
            float cv = cnorm[code];
            #pragma unroll
            for (int i = 0; i < 8; ++i) {
                float v = fmaf(-2.0f, acc[i][j], cv);
                if (v < runmin[i]) { runmin[i] = v; runidx[i] = code; }
            }
        }
    }
    // cross-thread reduce over tx per row; reuse As/Bs as scratch
    __syncthreads();
    float* Rv = &As[0][0];          // 128*16 floats
    int*   Ri = (int*)&Bs[0][0];
    #pragma unroll
    for (int i = 0; i < 8; ++i) {
        int row = ty * 8 + i;
        Rv[row * 16 + tx] = runmin[i];
        Ri[row * 16 + tx] = runidx[i];
    }
    __syncthreads();
    if (t < 128) {
        int row = t;
        float best = Rv[row * 16];
        int bi = Ri[row * 16];
        #pragma unroll
        for (int x = 1; x < 16; ++x) {
            float v = Rv[row * 16 + x];
            int idv = Ri[row * 16 + x];
            if (v < best || (v == best && idv < bi)) { best = v; bi = idv; }
        }
        pmin[(size_t)split * NR + rowbase + row] = best;
        pidx[(size_t)split * NR + rowbase + row] = bi;
    }
}

// ---------------- reduce over splits -> final ids (int + float output) ----------------
__global__ __launch_bounds__(256) void reduce_ids(
    const float* __restrict__ pmin, const int* __restrict__ pidx,
    int* __restrict__ ids, float* __restrict__ out_ids)
{
    int row = blockIdx.x * 256 + threadIdx.x;
    if (row >= NR) return;
    float best = pmin[row];
    int bi = pidx[row];
    #pragma unroll
    for (int s = 1; s < NSPLIT; ++s) {
        float v = pmin[(size_t)s * NR + row];
        int idv = pidx[(size_t)s * NR + row];
        if (v < best || (v == best && idv < bi)) { best = v; bi = idv; }
    }
    ids[row] = bi;
    out_ids[row] = (float)bi;
}

// ---------------- gather quantized + vq_loss ----------------
// 4 rows per block (one wave each). loss = 1.25 * mean((p-q)^2)
__global__ __launch_bounds__(256) void gather_loss(
    const float* __restrict__ P, const float* __restrict__ CB,
    const int* __restrict__ ids, float* __restrict__ outq,
    float* __restrict__ loss)
{
    const int t = threadIdx.x;
    const int lane = t & 63;
    const int w = t >> 6;
    const int row = blockIdx.x * 4 + w;
    const int id = ids[row];
    float4 q = *(const float4*)&CB[(size_t)id * ED + lane * 4];
    float4 p = *(const float4*)&P[(size_t)row * ED + lane * 4];
    *(float4*)&outq[(size_t)row * ED + lane * 4] = q;
    float dx = p.x - q.x, dy = p.y - q.y, dz = p.z - q.z, dw = p.w - q.w;
    float s = dx * dx + dy * dy + dz * dz + dw * dw;
    #pragma unroll
    for (int off = 32; off; off >>= 1) s += __shfl_down(s, off, 64);
    __shared__ float partial[4];
    if (lane == 0) partial[w] = s;
    __syncthreads();
    if (t == 0) {
        float tot = partial[0] + partial[1] + partial[2] + partial[3];
        atomicAdd(loss, tot * (1.25f / ((float)NR * (float)ED)));
    }
}

extern "C" void kernel_launch(void* const* d_in, const int* in_sizes, int n_in,
                              void* d_out, int out_size, void* d_ws, size_t ws_size,
                              hipStream_t stream) {
    const float* values = (const float*)d_in[0];   // [8,2048,1024]
    const float* W      = (const float*)d_in[1];   // [256,1024]
    const float* bias   = (const float*)d_in[2];   // [256]
    const float* CB     = (const float*)d_in[3];   // [8192,256]

    float* out      = (float*)d_out;
    float* out_q    = out;                                  // NR*ED
    float* out_ids  = out + (size_t)NR * ED;                // NR
    float* out_loss = out_ids + NR;                         // 1

    float* proj  = (float*)d_ws;                            // NR*ED f32 (16 MB)
    float* cnorm = proj + (size_t)NR * ED;                  // KC
    float* pmin  = cnorm + KC;                              // NSPLIT*NR
    int*   pidx  = (int*)(pmin + (size_t)NSPLIT * NR);      // NSPLIT*NR
    int*   ids   = pidx + (size_t)NSPLIT * NR;              // NR

    proj_kernel<<<dim3(NR / 64, ED / 64), 256, 0, stream>>>(values, W, bias, proj);
    cnorm_kernel<<<KC / 4, 256, 0, stream>>>(CB, cnorm);
    dist_kernel<<<dim3(NR / 128, NSPLIT), 256, 0, stream>>>(proj, CB, cnorm, pmin, pidx);
    reduce_ids<<<NR / 256, 256, 0, stream>>>(pmin, pidx, ids, out_ids);
    hipMemsetAsync(out_loss, 0, sizeof(float), stream);
    gather_loss<<<NR / 4, 256, 0, stream>>>(proj, CB, ids, out_q, out_loss);
}

// Round 2
// 1061.986 us; speedup vs baseline: 1.0240x; 1.0240x over previous
//
#include <hip/hip_runtime.h>

#define NR 16384   // B*S rows
#define VD 1024    // value dim
#define ED 256     // embed dim
#define KC 8192    // codebook size
#define NSPLIT 8   // code-range splits for the distance kernel

// ---------------- projection: C[r][e] = sum_v A[r][v]*W[e][v] + b[e] ----------------
// 64x64 tile, 256 threads, 4x4 micro-tile, depth chunks of 32.
// LDS tiles XOR-swizzled: element (d, c) stored at col c ^ ((d>>2)<<2).
__global__ __launch_bounds__(256) void proj_kernel(
    const float* __restrict__ A, const float* __restrict__ W,
    const float* __restrict__ bias, float* __restrict__ C)
{
    __shared__ float As[32][64];
    __shared__ float Bs[32][64];
    const int rowbase = blockIdx.x * 64;
    const int colbase = blockIdx.y * 64;
    const int t = threadIdx.x;
    const int tx = t & 15, ty = t >> 4;
    float acc[4][4] = {};
    for (int dc = 0; dc < VD; dc += 32) {
        #pragma unroll
        for (int i = 0; i < 2; ++i) {
            int idx = i * 256 + t;        // 0..511
            int r  = idx >> 3;            // 0..63
            int dq = idx & 7;             // depth quad
            int col = r ^ (dq << 2);      // swizzled col (swz = ((dq*4+c)>>2)<<2 = dq<<2)
            float4 va = *(const float4*)&A[(size_t)(rowbase + r) * VD + dc + dq * 4];
            As[dq*4+0][col] = va.x; As[dq*4+1][col] = va.y;
            As[dq*4+2][col] = va.z; As[dq*4+3][col] = va.w;
            float4 vw = *(const float4*)&W[(size_t)(colbase + r) * VD + dc + dq * 4];
            Bs[dq*4+0][col] = vw.x; Bs[dq*4+1][col] = vw.y;
            Bs[dq*4+2][col] = vw.z; Bs[dq*4+3][col] = vw.w;
        }
        __syncthreads();
        #pragma unroll
        for (int d = 0; d < 32; ++d) {
            const int s = (d >> 2) << 2;
            float a[4], bb[4];
            *(float4*)a  = *(const float4*)&As[d][(ty * 4) ^ s];
            *(float4*)bb = *(const float4*)&Bs[d][(tx * 4) ^ s];
            #pragma unroll
            for (int i = 0; i < 4; ++i)
                #pragma unroll
                for (int j = 0; j < 4; ++j)
                    acc[i][j] = fmaf(a[i], bb[j], acc[i][j]);
        }
        __syncthreads();
    }
    #pragma unroll
    for (int i = 0; i < 4; ++i) {
        int row = rowbase + ty * 4 + i;
        #pragma unroll
        for (int j = 0; j < 4; ++j) {
            int col = colbase + tx * 4 + j;
            C[(size_t)row * ED + col] = acc[i][j] + bias[col];
        }
    }
}

// ---------------- codebook norms: cnorm[k] = sum_e CB[k][e]^2 (f64 accum) ----------------
__global__ __launch_bounds__(256) void cnorm_kernel(
    const float* __restrict__ CB, float* __restrict__ cnorm)
{
    const int t = threadIdx.x;
    const int lane = t & 63;
    const int w = t >> 6;
    const int code = blockIdx.x * 4 + w;
    float4 c = *(const float4*)&CB[(size_t)code * ED + lane * 4];
    double s = (double)c.x * c.x + (double)c.y * c.y + (double)c.z * c.z + (double)c.w * c.w;
    #pragma unroll
    for (int off = 32; off; off >>= 1) s += __shfl_down(s, off, 64);
    if (lane == 0) cnorm[code] = (float)s;
}

// ---------------- fused distance + argmin ----------------
// d2(r,k) = cnorm[k] - 2 * dot(P[r], CB[k])   (||p||^2 dropped: constant per row)
// 128 rows x 128 codes tile, 256 threads, 8x8 micro.
// Thread (tx,ty) owns rows ty*8..+7 and codes {tx*4..+3, 64+tx*4..+3}.
// LDS XOR-swizzle as in proj_kernel.
__global__ __launch_bounds__(256, 4) void dist_kernel(
    const float* __restrict__ P, const float* __restrict__ CB,
    const float* __restrict__ cnorm,
    float* __restrict__ pmin, int* __restrict__ pidx)
{
    __shared__ float As[32][128];
    __shared__ float Bs[32][128];
    const int rowbase = blockIdx.x * 128;
    const int split = blockIdx.y;
    const int codebase0 = split * (KC / NSPLIT);
    const int t = threadIdx.x;
    const int tx = t & 15, ty = t >> 4;
    float runmin[8];
    int runidx[8];
    #pragma unroll
    for (int i = 0; i < 8; ++i) { runmin[i] = 3.4e38f; runidx[i] = 0x7fffffff; }

    for (int kc = 0; kc < KC / NSPLIT; kc += 128) {
        const int codebase = codebase0 + kc;
        float acc[8][8] = {};
        for (int dc = 0; dc < ED; dc += 32) {
            #pragma unroll
            for (int i = 0; i < 4; ++i) {
                int idx = i * 256 + t;    // 0..1023
                int r  = idx >> 3;        // 0..127
                int dq = idx & 7;
                int col = r ^ (dq << 2);  // swizzled col
                float4 va = *(const float4*)&P[(size_t)(rowbase + r) * ED + dc + dq * 4];
                As[dq*4+0][col] = va.x; As[dq*4+1][col] = va.y;
                As[dq*4+2][col] = va.z; As[dq*4+3][col] = va.w;
                float4 vb = *(const float4*)&CB[(size_t)(codebase + r) * ED + dc + dq * 4];
                Bs[dq*4+0][col] = vb.x; Bs[dq*4+1][col] = vb.y;
                Bs[dq*4+2][col] = vb.z; Bs[dq*4+3][col] = vb.w;
            }
            __syncthreads();
            #pragma unroll
            for (int d = 0; d < 32; ++d) {
                const int s = (d >> 2) << 2;
                float a[8], bb[8];
                *(float4*)&a[0]  = *(const float4*)&As[d][(ty * 8) ^ s];
                *(float4*)&a[4]  = *(const float4*)&As[d][(ty * 8 + 4) ^ s];
                *(float4*)&bb[0] = *(const float4*)&Bs[d][(tx * 4) ^ s];
                *(float4*)&bb[4] = *(const float4*)&Bs[d][(64 + tx * 4) ^ s];
                #pragma unroll
                for (int i = 0; i < 8; ++i)
                    #pragma unroll
                    for (int j = 0; j < 8; ++j)
                        acc[i][j] = fmaf(a[i], bb[j], acc[i][j]);
            }
            __syncthreads();
        }
        // argmin epilogue; per-thread codes ascend (tx*4+j then 64+tx*4+j) -> strict < keeps first
        #pragma unroll
        for (int j = 0; j < 8; ++j) {
            int code = codebase + ((j < 4) ? (tx * 4 + j) : (64 + tx * 4 + (j - 4)));
            float cv = cnorm[code];
            #pragma unroll
            for (int i = 0; i < 8; ++i) {
                float v = fmaf(-2.0f, acc[i][j], cv);
                if (v < runmin[i]) { runmin[i] = v; runidx[i] = code; }
            }
        }
    }
    // cross-thread reduce over tx per row; reuse As/Bs as scratch
    __syncthreads();
    float* Rv = &As[0][0];          // 128*16 floats
    int*   Ri = (int*)&Bs[0][0];
    #pragma unroll
    for (int i = 0; i < 8; ++i) {
        int row = ty * 8 + i;
        Rv[row * 16 + tx] = runmin[i];
        Ri[row * 16 + tx] = runidx[i];
    }
    __syncthreads();
    if (t < 128) {
        int row = t;
        float best = Rv[row * 16];
        int bi = Ri[row * 16];
        #pragma unroll
        for (int x = 1; x < 16; ++x) {
            float v = Rv[row * 16 + x];
            int idv = Ri[row * 16 + x];
            if (v < best || (v == best && idv < bi)) { best = v; bi = idv; }
        }
        pmin[(size_t)split * NR + rowbase + row] = best;
        pidx[(size_t)split * NR + rowbase + row] = bi;
    }
}

// ---------------- reduce over splits -> final ids (int + float output) ----------------
__global__ __launch_bounds__(256) void reduce_ids(
    const float* __restrict__ pmin, const int* __restrict__ pidx,
    int* __restrict__ ids, float* __restrict__ out_ids)
{
    int row = blockIdx.x * 256 + threadIdx.x;
    if (row >= NR) return;
    float best = pmin[row];
    int bi = pidx[row];
    #pragma unroll
    for (int s = 1; s < NSPLIT; ++s) {
        float v = pmin[(size_t)s * NR + row];
        int idv = pidx[(size_t)s * NR + row];
        if (v < best || (v == best && idv < bi)) { best = v; bi = idv; }
    }
    ids[row] = bi;
    out_ids[row] = (float)bi;
}

// ---------------- gather quantized + vq_loss ----------------
// 4 rows per block (one wave each). loss = 1.25 * mean((p-q)^2)
__global__ __launch_bounds__(256) void gather_loss(
    const float* __restrict__ P, const float* __restrict__ CB,
    const int* __restrict__ ids, float* __restrict__ outq,
    float* __restrict__ loss)
{
    const int t = threadIdx.x;
    const int lane = t & 63;
    const int w = t >> 6;
    const int row = blockIdx.x * 4 + w;
    const int id = ids[row];
    float4 q = *(const float4*)&CB[(size_t)id * ED + lane * 4];
    float4 p = *(const float4*)&P[(size_t)row * ED + lane * 4];
    *(float4*)&outq[(size_t)row * ED + lane * 4] = q;
    float dx = p.x - q.x, dy = p.y - q.y, dz = p.z - q.z, dw = p.w - q.w;
    float s = dx * dx + dy * dy + dz * dz + dw * dw;
    #pragma unroll
    for (int off = 32; off; off >>= 1) s += __shfl_down(s, off, 64);
    __shared__ float partial[4];
    if (lane == 0) partial[w] = s;
    __syncthreads();
    if (t == 0) {
        float tot = partial[0] + partial[1] + partial[2] + partial[3];
        atomicAdd(loss, tot * (1.25f / ((float)NR * (float)ED)));
    }
}

extern "C" void kernel_launch(void* const* d_in, const int* in_sizes, int n_in,
                              void* d_out, int out_size, void* d_ws, size_t ws_size,
                              hipStream_t stream) {
    const float* values = (const float*)d_in[0];   // [8,2048,1024]
    const float* W      = (const float*)d_in[1];   // [256,1024]
    const float* bias   = (const float*)d_in[2];   // [256]
    const float* CB     = (const float*)d_in[3];   // [8192,256]

    float* out      = (float*)d_out;
    float* out_q    = out;                                  // NR*ED
    float* out_ids  = out + (size_t)NR * ED;                // NR
    float* out_loss = out_ids + NR;                         // 1

    float* proj  = (float*)d_ws;                            // NR*ED f32 (16 MB)
    float* cnorm = proj + (size_t)NR * ED;                  // KC
    float* pmin  = cnorm + KC;                              // NSPLIT*NR
    int*   pidx  = (int*)(pmin + (size_t)NSPLIT * NR);      // NSPLIT*NR
    int*   ids   = pidx + (size_t)NSPLIT * NR;              // NR

    proj_kernel<<<dim3(NR / 64, ED / 64), 256, 0, stream>>>(values, W, bias, proj);
    cnorm_kernel<<<KC / 4, 256, 0, stream>>>(CB, cnorm);
    dist_kernel<<<dim3(NR / 128, NSPLIT), 256, 0, stream>>>(proj, CB, cnorm, pmin, pidx);
    reduce_ids<<<NR / 256, 256, 0, stream>>>(pmin, pidx, ids, out_ids);
    hipMemsetAsync(out_loss, 0, sizeof(float), stream);
    gather_loss<<<NR / 4, 256, 0, stream>>>(proj, CB, ids, out_q, out_loss);
}

// Round 3
// 545.697 us; speedup vs baseline: 1.9927x; 1.9461x over previous
//
#include <hip/hip_runtime.h>

typedef __attribute__((ext_vector_type(8))) short bf16x8;
typedef __attribute__((ext_vector_type(4))) float f32x4;
typedef unsigned int uint32;
typedef unsigned long long ull;

#define NR 16384   // B*S rows
#define VD 1024    // value dim
#define ED 256     // embed dim
#define KC 8192    // codebook size
#define NCB 64     // KC/128 code blocks
#define DELTA 1.0f // rescore margin (>> 2*max bf16 noise ~0.36)

__device__ __forceinline__ uint32 f2u(float f){ return __float_as_uint(f); }
__device__ __forceinline__ float u2f(uint32 u){ return __uint_as_float(u); }

// pack two f32 -> two bf16 (RNE) into one uint (lo16 = first elem)
__device__ __forceinline__ uint32 pkbf(float lo, float hi){
  uint32 a = __float_as_uint(lo); a += 0x7fffu + ((a >> 16) & 1u);
  uint32 b = __float_as_uint(hi); b += 0x7fffu + ((b >> 16) & 1u);
  return (a >> 16) | (b & 0xffff0000u);
}

// swizzled LDS byte offset for (row, kbyte) in a [128 rows][64 B] bf16 tile.
// 16B-unit swizzle: unit' = (unit + row/2) & 3 -> rows 0..7 hit 8 distinct
// bank quads for any fixed unit (2-way over 16 lanes = free).
__device__ __forceinline__ int swz(int row, int kbyte){
  return row * 64 + ((((kbyte >> 4) + (row >> 1)) & 3) << 4) + (kbyte & 15);
}

// ---------------- projection (f32, exact): C[r][e] = sum_v A[r][v]*W[e][v] + b[e] ----
__global__ __launch_bounds__(256) void proj_kernel(
    const float* __restrict__ A, const float* __restrict__ W,
    const float* __restrict__ bias, float* __restrict__ C)
{
    __shared__ float As[32][64];
    __shared__ float Bs[32][64];
    const int rowbase = blockIdx.x * 64;
    const int colbase = blockIdx.y * 64;
    const int t = threadIdx.x;
    const int tx = t & 15, ty = t >> 4;
    float acc[4][4] = {};
    for (int dc = 0; dc < VD; dc += 32) {
        #pragma unroll
        for (int i = 0; i < 2; ++i) {
            int idx = i * 256 + t;
            int r  = idx >> 3;
            int dq = idx & 7;
            int col = r ^ (dq << 2);
            float4 va = *(const float4*)&A[(size_t)(rowbase + r) * VD + dc + dq * 4];
            As[dq*4+0][col] = va.x; As[dq*4+1][col] = va.y;
            As[dq*4+2][col] = va.z; As[dq*4+3][col] = va.w;
            float4 vw = *(const float4*)&W[(size_t)(colbase + r) * VD + dc + dq * 4];
            Bs[dq*4+0][col] = vw.x; Bs[dq*4+1][col] = vw.y;
            Bs[dq*4+2][col] = vw.z; Bs[dq*4+3][col] = vw.w;
        }
        __syncthreads();
        #pragma unroll
        for (int d = 0; d < 32; ++d) {
            const int s = (d >> 2) << 2;
            float a[4], bb[4];
            *(float4*)a  = *(const float4*)&As[d][(ty * 4) ^ s];
            *(float4*)bb = *(const float4*)&Bs[d][(tx * 4) ^ s];
            #pragma unroll
            for (int i = 0; i < 4; ++i)
                #pragma unroll
                for (int j = 0; j < 4; ++j)
                    acc[i][j] = fmaf(a[i], bb[j], acc[i][j]);
        }
        __syncthreads();
    }
    #pragma unroll
    for (int i = 0; i < 4; ++i) {
        int row = rowbase + ty * 4 + i;
        #pragma unroll
        for (int j = 0; j < 4; ++j) {
            int col = colbase + tx * 4 + j;
            C[(size_t)row * ED + col] = acc[i][j] + bias[col];
        }
    }
}

// ---------------- codebook norms (f64 accum) ----------------
__global__ __launch_bounds__(256) void cnorm_kernel(
    const float* __restrict__ CB, float* __restrict__ cnorm)
{
    const int t = threadIdx.x;
    const int lane = t & 63;
    const int w = t >> 6;
    const int code = blockIdx.x * 4 + w;
    float4 c = *(const float4*)&CB[(size_t)code * ED + lane * 4];
    double s = (double)c.x * c.x + (double)c.y * c.y + (double)c.z * c.z + (double)c.w * c.w;
    #pragma unroll
    for (int off = 32; off; off >>= 1) s += __shfl_down(s, off, 64);
    if (lane == 0) cnorm[code] = (float)s;
}

// ---------------- bf16 MFMA distance prefilter ----------------
// approx_d2(r,k) = cnorm[k] - 2 * bf16dot(P[r], CB[k]).
// Block: 128 rows x 128 codes, 4 waves (2x2), wave tile 64x64 = 4x4 frags of
// 16x16x32. Reg-staged f32->bf16 into swizzled LDS. Epilogue keeps top-2
// (min1,idx1,min2,idx2) per (row, 128-code block) -> top2[row][colblk].
__global__ __launch_bounds__(256) void mfma_dist(
    const float* __restrict__ P, const float* __restrict__ CBF,
    const float* __restrict__ cnorm, uint4* __restrict__ top2)
{
  __shared__ uint4 AshV[512];      // 8 KB bf16 A tile [128][32]
  __shared__ uint4 BshV[512];      // 8 KB bf16 B tile [128][32]
  __shared__ uint4 msh[128][2];    // per-row top2 per wave-column

  const int rowbase = blockIdx.x * 128;
  const int colbase = blockIdx.y * 128;
  const int t = threadIdx.x;
  const int l = t & 63;
  const int w = t >> 6;
  const int wr = w >> 1, wc = w & 1;
  char* Ab = (char*)AshV;
  char* Bb = (char*)BshV;

  // staging assignment: thread t -> row t>>1, 16 f32 elems at offset (t&1)*16
  const int srow = t >> 1;
  const int sk   = (t & 1) * 16;
  const float* ap = P   + (size_t)(rowbase + srow) * ED + sk;
  const float* bp = CBF + (size_t)(colbase + srow) * ED + sk;
  const int wo0 = swz(srow, sk * 2);
  const int wo1 = swz(srow, sk * 2 + 16);

  f32x4 acc[4][4];
  #pragma unroll
  for (int i = 0; i < 4; ++i)
    #pragma unroll
    for (int j = 0; j < 4; ++j)
      acc[i][j] = (f32x4){0.f, 0.f, 0.f, 0.f};

  const int g = l >> 4, c0 = l & 15;
  int aoff[4], boff[4];
  #pragma unroll
  for (int ri = 0; ri < 4; ++ri) aoff[ri] = swz(wr * 64 + ri * 16 + c0, g * 16);
  #pragma unroll
  for (int cj = 0; cj < 4; ++cj) boff[cj] = swz(wc * 64 + cj * 16 + c0, g * 16);

  for (int dc = 0; dc < ED; dc += 32) {
    float4 a0 = *(const float4*)(ap + dc);
    float4 a1 = *(const float4*)(ap + dc + 4);
    float4 a2 = *(const float4*)(ap + dc + 8);
    float4 a3 = *(const float4*)(ap + dc + 12);
    float4 b0 = *(const float4*)(bp + dc);
    float4 b1 = *(const float4*)(bp + dc + 4);
    float4 b2 = *(const float4*)(bp + dc + 8);
    float4 b3 = *(const float4*)(bp + dc + 12);
    uint4 wA0 = make_uint4(pkbf(a0.x,a0.y), pkbf(a0.z,a0.w), pkbf(a1.x,a1.y), pkbf(a1.z,a1.w));
    uint4 wA1 = make_uint4(pkbf(a2.x,a2.y), pkbf(a2.z,a2.w), pkbf(a3.x,a3.y), pkbf(a3.z,a3.w));
    uint4 wB0 = make_uint4(pkbf(b0.x,b0.y), pkbf(b0.z,b0.w), pkbf(b1.x,b1.y), pkbf(b1.z,b1.w));
    uint4 wB1 = make_uint4(pkbf(b2.x,b2.y), pkbf(b2.z,b2.w), pkbf(b3.x,b3.y), pkbf(b3.z,b3.w));
    *(uint4*)(Ab + wo0) = wA0;
    *(uint4*)(Ab + wo1) = wA1;
    *(uint4*)(Bb + wo0) = wB0;
    *(uint4*)(Bb + wo1) = wB1;
    __syncthreads();
    bf16x8 af[4], bfr[4];
    #pragma unroll
    for (int ri = 0; ri < 4; ++ri) af[ri]  = *(bf16x8*)(Ab + aoff[ri]);
    #pragma unroll
    for (int cj = 0; cj < 4; ++cj) bfr[cj] = *(bf16x8*)(Bb + boff[cj]);
    #pragma unroll
    for (int ri = 0; ri < 4; ++ri)
      #pragma unroll
      for (int cj = 0; cj < 4; ++cj)
        acc[ri][cj] = __builtin_amdgcn_mfma_f32_16x16x32_bf16(af[ri], bfr[cj], acc[ri][cj], 0, 0, 0);
    __syncthreads();
  }

  // epilogue: per-row top2 over the 128 codes of this block
  float cn[4]; uint32 cd[4];
  #pragma unroll
  for (int cj = 0; cj < 4; ++cj) {
    cd[cj] = colbase + wc * 64 + cj * 16 + c0;
    cn[cj] = cnorm[cd[cj]];
  }
  #pragma unroll
  for (int ri = 0; ri < 4; ++ri) {
    #pragma unroll
    for (int r = 0; r < 4; ++r) {
      float m1 = 3.4e38f, m2 = 3.4e38f; uint32 i1 = 0, i2 = 0;
      #pragma unroll
      for (int cj = 0; cj < 4; ++cj) {
        float v = fmaf(-2.f, acc[ri][cj][r], cn[cj]);
        if (v < m1)      { m2 = m1; i2 = i1; m1 = v; i1 = cd[cj]; }
        else if (v < m2) { m2 = v;  i2 = cd[cj]; }
      }
      // merge across the 16 lanes that share this row
      #pragma unroll
      for (int mask = 1; mask < 16; mask <<= 1) {
        float  om1 = __shfl_xor(m1, mask);
        uint32 oi1 = (uint32)__shfl_xor((int)i1, mask);
        float  om2 = __shfl_xor(m2, mask);
        uint32 oi2 = (uint32)__shfl_xor((int)i2, mask);
        if (om1 < m1 || (om1 == m1 && oi1 < i1)) {
          float nm2; uint32 ni2;
          if (m1 < om2 || (m1 == om2 && i1 < oi2)) { nm2 = m1; ni2 = i1; }
          else                                     { nm2 = om2; ni2 = oi2; }
          m1 = om1; i1 = oi1; m2 = nm2; i2 = ni2;
        } else {
          if (om1 < m2 || (om1 == m2 && oi1 < i2)) { m2 = om1; i2 = oi1; }
        }
      }
      if (c0 == 0)
        msh[wr * 64 + ri * 16 + g * 4 + r][wc] = make_uint4(f2u(m1), i1, f2u(m2), i2);
    }
  }
  __syncthreads();
  if (t < 128) {
    uint4 A = msh[t][0], B = msh[t][1];
    uint4 R;
    float a1 = u2f(A.x), b1 = u2f(B.x);
    if (b1 < a1 || (b1 == a1 && B.y < A.y)) {
      R.x = B.x; R.y = B.y;
      float b2 = u2f(B.z);
      if (a1 < b2 || (a1 == b2 && A.y < B.w)) { R.z = A.x; R.w = A.y; }
      else                                    { R.z = B.z; R.w = B.w; }
    } else {
      R.x = A.x; R.y = A.y;
      float a2 = u2f(A.z);
      if (b1 < a2 || (b1 == a2 && B.y < A.w)) { R.z = B.x; R.w = B.y; }
      else                                    { R.z = A.z; R.w = A.w; }
    }
    top2[(size_t)(rowbase + t) * NCB + blockIdx.y] = R;
  }
}

// ---------------- exact rescore: 1 wave per row ----------------
__global__ __launch_bounds__(256) void rescore_kernel(
    const uint4* __restrict__ top2, const float* __restrict__ P,
    const float* __restrict__ CBF, const float* __restrict__ cnorm,
    int* __restrict__ ids, float* __restrict__ out_ids)
{
  const int t = threadIdx.x, l = t & 63, w = t >> 6;
  const int row = blockIdx.x * 4 + w;
  uint4 e = top2[(size_t)row * NCB + l];
  float m1 = u2f(e.x), m2 = u2f(e.z);
  float rm = m1;
  #pragma unroll
  for (int mask = 1; mask < 64; mask <<= 1) rm = fminf(rm, __shfl_xor(rm, mask));
  const float thr = rm + DELTA;
  ull best = ~0ull;
  const float4* pr = (const float4*)(P + (size_t)row * ED);
  #pragma unroll
  for (int cand = 0; cand < 2; ++cand) {
    float  m   = cand ? m2  : m1;
    uint32 idx = cand ? e.w : e.y;
    if (m <= thr) {
      const float4* cr = (const float4*)(CBF + (size_t)idx * ED);
      double s0 = 0, s1 = 0, s2 = 0, s3 = 0;
      for (int q = 0; q < 64; q += 2) {
        float4 p = pr[q],     c = cr[q];
        float4 p2 = pr[q + 1], c2 = cr[q + 1];
        s0 += (double)p.x * c.x + (double)p.y * c.y;
        s1 += (double)p.z * c.z + (double)p.w * c.w;
        s2 += (double)p2.x * c2.x + (double)p2.y * c2.y;
        s3 += (double)p2.z * c2.z + (double)p2.w * c2.w;
      }
      double d2 = (double)cnorm[idx] - 2.0 * ((s0 + s1) + (s2 + s3));
      float f = (float)d2;
      uint32 b = __float_as_uint(f);
      uint32 o = (f >= 0.f) ? (b | 0x80000000u) : ~b;
      ull key = ((ull)o << 32) | (ull)idx;
      best = best < key ? best : key;
    }
  }
  #pragma unroll
  for (int mask = 1; mask < 64; mask <<= 1) {
    ull ob = __shfl_xor(best, mask);
    best = best < ob ? best : ob;
  }
  if (l == 0) {
    int id = (int)(best & 0xffffffffull);
    ids[row] = id;
    out_ids[row] = (float)id;
  }
}

// ---------------- gather quantized + vq_loss ----------------
__global__ __launch_bounds__(256) void gather_loss(
    const float* __restrict__ P, const float* __restrict__ CB,
    const int* __restrict__ ids, float* __restrict__ outq,
    float* __restrict__ loss)
{
    const int t = threadIdx.x;
    const int lane = t & 63;
    const int w = t >> 6;
    const int row = blockIdx.x * 4 + w;
    const int id = ids[row];
    float4 q = *(const float4*)&CB[(size_t)id * ED + lane * 4];
    float4 p = *(const float4*)&P[(size_t)row * ED + lane * 4];
    *(float4*)&outq[(size_t)row * ED + lane * 4] = q;
    float dx = p.x - q.x, dy = p.y - q.y, dz = p.z - q.z, dw = p.w - q.w;
    float s = dx * dx + dy * dy + dz * dz + dw * dw;
    #pragma unroll
    for (int off = 32; off; off >>= 1) s += __shfl_down(s, off, 64);
    __shared__ float partial[4];
    if (lane == 0) partial[w] = s;
    __syncthreads();
    if (t == 0) {
        float tot = partial[0] + partial[1] + partial[2] + partial[3];
        atomicAdd(loss, tot * (1.25f / ((float)NR * (float)ED)));
    }
}

extern "C" void kernel_launch(void* const* d_in, const int* in_sizes, int n_in,
                              void* d_out, int out_size, void* d_ws, size_t ws_size,
                              hipStream_t stream) {
    const float* values = (const float*)d_in[0];   // [8,2048,1024]
    const float* W      = (const float*)d_in[1];   // [256,1024]
    const float* bias   = (const float*)d_in[2];   // [256]
    const float* CB     = (const float*)d_in[3];   // [8192,256]

    float* out      = (float*)d_out;
    float* out_q    = out;                         // NR*ED (reused as top2 scratch first)
    float* out_ids  = out + (size_t)NR * ED;       // NR
    float* out_loss = out_ids + NR;                // 1

    float* proj  = (float*)d_ws;                   // NR*ED f32 (16 MB)
    float* cnorm = proj + (size_t)NR * ED;         // KC
    int*   ids   = (int*)(cnorm + KC);             // NR

    // top2 candidates live in the (not-yet-written) quantized output region:
    // NR * NCB * 16 B == NR * ED * 4 B exactly.
    uint4* top2 = (uint4*)out_q;

    proj_kernel<<<dim3(NR / 64, ED / 64), 256, 0, stream>>>(values, W, bias, proj);
    cnorm_kernel<<<KC / 4, 256, 0, stream>>>(CB, cnorm);
    mfma_dist<<<dim3(NR / 128, KC / 128), 256, 0, stream>>>(proj, CB, cnorm, top2);
    rescore_kernel<<<NR / 4, 256, 0, stream>>>(top2, proj, CB, cnorm, ids, out_ids);
    hipMemsetAsync(out_loss, 0, sizeof(float), stream);
    gather_loss<<<NR / 4, 256, 0, stream>>>(proj, CB, ids, out_q, out_loss);
}